// Round 10
// baseline (925.503 us; speedup 1.0000x reference)
//
#include <hip/hip_runtime.h>
#include <math.h>

// HungarianLoss: B=128 samples, each a 192x192 LSAP on
// cost[q][j] = -softmax(pred[q])[tgt[j]], then mean CE with matched classes.
//
// R10 = R5 (best @837us: sequential JV shortest augmenting path, zero duals,
// state in registers 3/lane, fresh packed-key argmin each round) with ONE
// change: key low byte = row4col[j]+1 instead of j. The reduce winner then
// directly yields the next row (i = (mn&255)-1; 0 = sink), removing the
// GET_I3(yy)+readlane hop from the serial chain. Settle = lane-local pk==mn;
// exact minVal recovered by ballot+readlane AFTER i is known (scheduled into
// the next ds_read's latency shadow). All other logic byte-identical to R5.

#define BB 128
#define QQ 192
#define CC 512
#define NBIG 1e30f

template<int CTRL>
__device__ __forceinline__ int dpp_mov(int x) {
    return __builtin_amdgcn_update_dpp(x, x, CTRL, 0xf, 0xf, false);
}

__device__ __forceinline__ int readlane_i(int v, int l) {
    return __builtin_amdgcn_readlane(v, l);
}
__device__ __forceinline__ float readlane_f(float v, int l) {
    return __int_as_float(__builtin_amdgcn_readlane(__float_as_int(v), l));
}
__device__ __forceinline__ unsigned umin_(unsigned a, unsigned b) { return a < b ? a : b; }

// fill-phase reduces (validated R1-R9)
__device__ __forceinline__ float wave_max64(float x) {
    x = fmaxf(x, __int_as_float(dpp_mov<0x111>(__float_as_int(x))));
    x = fmaxf(x, __int_as_float(dpp_mov<0x112>(__float_as_int(x))));
    x = fmaxf(x, __int_as_float(dpp_mov<0x114>(__float_as_int(x))));
    x = fmaxf(x, __int_as_float(dpp_mov<0x118>(__float_as_int(x))));
    x = fmaxf(x, __int_as_float(dpp_mov<0x142>(__float_as_int(x))));
    x = fmaxf(x, __int_as_float(dpp_mov<0x143>(__float_as_int(x))));
    return __int_as_float(__builtin_amdgcn_readlane(__float_as_int(x), 63));
}
__device__ __forceinline__ float wave_sum64(float x) {
    x += __int_as_float(dpp_mov<0x111>(__float_as_int(x)));
    x += __int_as_float(dpp_mov<0x112>(__float_as_int(x)));
    x += __int_as_float(dpp_mov<0x114>(__float_as_int(x)));
    x += __int_as_float(dpp_mov<0x118>(__float_as_int(x)));
    x += __int_as_float(dpp_mov<0x142>(__float_as_int(x)));
    x += __int_as_float(dpp_mov<0x143>(__float_as_int(x)));
    return __int_as_float(__builtin_amdgcn_readlane(__float_as_int(x), 63));
}

// packed-key min over 64 lanes (R5-validated): 4 DPP row_shr + 4 readlane + s_min
__device__ __forceinline__ unsigned wave_min_pk(unsigned x) {
    x = umin_(x, (unsigned)dpp_mov<0x111>((int)x));
    x = umin_(x, (unsigned)dpp_mov<0x112>((int)x));
    x = umin_(x, (unsigned)dpp_mov<0x114>((int)x));
    x = umin_(x, (unsigned)dpp_mov<0x118>((int)x));
    unsigned a = (unsigned)readlane_i((int)x, 15);
    unsigned b = (unsigned)readlane_i((int)x, 31);
    unsigned c = (unsigned)readlane_i((int)x, 47);
    unsigned d = (unsigned)readlane_i((int)x, 63);
    return umin_(umin_(a, b), umin_(c, d));
}

// sign-aware monotonic float->u32 key (R5-validated)
__device__ __forceinline__ unsigned fkey(float f) {
    unsigned b = __float_as_uint(f);
    return b ^ (((unsigned)((int)b >> 31)) | 0x80000000u);
}

// distributed-register accessors (idx -> owner lane idx&63, slot idx>>6)
#define GET_I3(a, idx) readlane_i((((idx)>>6)==0) ? a##0 : ((((idx)>>6)==1) ? a##1 : a##2), (idx)&63)
#define GET_F3(a, idx) readlane_f((((idx)>>6)==0) ? a##0 : ((((idx)>>6)==1) ? a##1 : a##2), (idx)&63)
#define SET_I3(a, idx, val) do { const int _s=(idx)>>6, _l=(idx)&63; \
    if (_s==0) { if (lane==_l) a##0=(val); } \
    else if (_s==1) { if (lane==_l) a##1=(val); } \
    else { if (lane==_l) a##2=(val); } } while(0)

__launch_bounds__(256)
__global__ void hungarian_kernel(const float* __restrict__ pred,
                                 const int* __restrict__ targets,
                                 float* __restrict__ ws_part) {
    const int b = blockIdx.x;
    const int lane = threadIdx.x & 63;
    const int wv = threadIdx.x >> 6;

    extern __shared__ float smem[];
    float* cost    = smem;                   // [QQ*QQ] read-only after fill
    float* spc_lds = cost + QQ * QQ;         // [QQ] per-solve spc dump
    float* lse_lds = spc_lds + QQ;           // [QQ]
    int*   tgt_lds = (int*)(lse_lds + QQ);   // [QQ]

    // ---- targets ----
    const int t0 = targets[b * QQ + lane];
    const int t1 = targets[b * QQ + lane + 64];
    const int t2 = targets[b * QQ + lane + 128];
    if (wv == 0) { tgt_lds[lane] = t0; tgt_lds[lane + 64] = t1; tgt_lds[lane + 128] = t2; }

    // ---- fill: 4 waves, 48 rows each (validated R4/R5) ----
    const float* predb = pred + (size_t)b * QQ * CC;
    {
        const int q0 = wv * 48, q1 = q0 + 48;
        float x[8];
        #pragma unroll
        for (int k = 0; k < 8; k++) x[k] = predb[(size_t)q0 * CC + lane + 64 * k];
        for (int q = q0; q < q1; q++) {
            const float* row = predb + (size_t)q * CC;
            float g0 = row[t0], g1 = row[t1], g2 = row[t2];
            float xn[8];
            if (q + 1 < q1) {
                const float* nrow = row + CC;
                #pragma unroll
                for (int k = 0; k < 8; k++) xn[k] = nrow[lane + 64 * k];
            }
            float mx = x[0];
            #pragma unroll
            for (int k = 1; k < 8; k++) mx = fmaxf(mx, x[k]);
            mx = wave_max64(mx);
            float s = 0.f;
            #pragma unroll
            for (int k = 0; k < 8; k++) s += expf(x[k] - mx);
            s = wave_sum64(s);
            float lse = mx + logf(s);
            if (lane == 0) lse_lds[q] = lse;
            cost[q * QQ + lane]       = -expf(g0 - lse);
            cost[q * QQ + lane + 64]  = -expf(g1 - lse);
            cost[q * QQ + lane + 128] = -expf(g2 - lse);
            #pragma unroll
            for (int k = 0; k < 8; k++) x[k] = xn[k];
        }
    }
    __syncthreads();
    if (wv != 0) return;
    // single wave from here: in-wave LDS ordering via waitcnt, no barriers.

    // ---- solver state: 3 rows + 3 cols per lane ----
    float u0 = 0.f, u1 = 0.f, u2 = 0.f;   // row duals
    float v0 = 0.f, v1 = 0.f, v2 = 0.f;   // col duals
    int   xx0 = -1, xx1 = -1, xx2 = -1;   // col4row
    int   yy0 = -1, yy1 = -1, yy2 = -1;   // row4col

    // ---- sequential JV shortest augmenting path (R5 semantics) ----
    for (int cur = 0; cur < QQ; cur++) {
        float spc0 = NBIG, spc1 = NBIG, spc2 = NBIG;
        int   p0 = 0, p1 = 0, p2 = 0;
        int   sc0 = 0, sc1 = 0, sc2 = 0;
        unsigned long long SRm0 = 0, SRm1 = 0, SRm2 = 0;  // scanned-row masks
        // key low-byte fields: row4col+1 (static within a search; 0 = free col)
        const unsigned yf0 = (unsigned)(yy0 + 1);
        const unsigned yf1 = (unsigned)(yy1 + 1);
        const unsigned yf2 = (unsigned)(yy2 + 1);
        int   i = cur;
        float minVal = 0.f;
        int   sink;

        while (true) {
            {   // SR[i] (scalar)
                const int is = i >> 6, il = i & 63;
                if (is == 0)      SRm0 |= 1ull << il;
                else if (is == 1) SRm1 |= 1ull << il;
                else              SRm2 |= 1ull << il;
            }
            // issue the row read (address depends only on i)
            const float* crow = cost + i * QQ;
            const float cA = crow[lane];
            const float cB = crow[lane + 64];
            const float cD = crow[lane + 128];
            const float ui = GET_F3(u, i);   // in the ds_read shadow

            // relax (R5 exact ordering + guard semantics)
            float rA = ((minVal + cA) - ui) - v0;  rA = sc0 ? NBIG : rA;
            if (rA < spc0) { spc0 = rA; p0 = i; }
            float rB = ((minVal + cB) - ui) - v1;  rB = sc1 ? NBIG : rB;
            if (rB < spc1) { spc1 = rB; p1 = i; }
            float rD = ((minVal + cD) - ui) - v2;  rD = sc2 ? NBIG : rD;
            if (rD < spc2) { spc2 = rD; p2 = i; }

            // fresh packed keys (R5); low byte = row4col+1 so the winner key
            // carries the next row directly
            const unsigned pkA = sc0 ? 0xFFFFFFFFu : ((fkey(spc0) & 0xFFFFFF00u) | yf0);
            const unsigned pkB = sc1 ? 0xFFFFFFFFu : ((fkey(spc1) & 0xFFFFFF00u) | yf1);
            const unsigned pkD = sc2 ? 0xFFFFFFFFu : ((fkey(spc2) & 0xFFFFFF00u) | yf2);
            const unsigned mn = wave_min_pk(umin_(umin_(pkA, pkB), pkD));
            const int rjf = (int)(mn & 255u);

            // settle the winner: lane-local key compare (keys unique mid-search)
            const int m0 = (pkA == mn), m1 = (pkB == mn), m2 = (pkD == mn);
            sc0 |= m0; sc1 |= m1; sc2 |= m2;

            if (rjf == 0) {
                // sink: winner is a free column. Recover col + exact minVal.
                // (Not settled -> exact: reference's sink v-delta is 0.)
                const unsigned long long b0 = __ballot(m0);
                const unsigned long long b1 = __ballot(m1);
                const unsigned long long b2 = __ballot(m2);
                int ol;
                if (b0)      { ol = __ffsll(b0) - 1; sink = ol;       minVal = readlane_f(spc0, ol); }
                else if (b1) { ol = __ffsll(b1) - 1; sink = ol + 64;  minVal = readlane_f(spc1, ol); }
                else         { ol = __ffsll(b2) - 1; sink = ol + 128; minVal = readlane_f(spc2, ol); }
                // undo the settle of the sink (reference leaves it equivalent;
                // epilogue v-update for sink would be -0 anyway, but keep sc
                // consistent with R5 by leaving it settled)
                break;
            }
            i = rjf - 1;   // next row known IMMEDIATELY after the reduce

            // exact minVal for the next round, recovered in the next read's
            // shadow (no dependence on the next ds_read)
            const unsigned long long b0 = __ballot(m0);
            const unsigned long long b1 = __ballot(m1);
            const unsigned long long b2 = __ballot(m2);
            if (b0)      minVal = readlane_f(spc0, __ffsll(b0) - 1);
            else if (b1) minVal = readlane_f(spc1, __ffsll(b1) - 1);
            else         minVal = readlane_f(spc2, __ffsll(b2) - 1);
        }

        // ---- dual updates (R5) ----
        u0 += (cur == lane) ? minVal : 0.f;
        u1 += (cur == lane + 64) ? minVal : 0.f;
        u2 += (cur == lane + 128) ? minVal : 0.f;
        spc_lds[lane] = spc0; spc_lds[lane + 64] = spc1; spc_lds[lane + 128] = spc2;
        const int f0 = (int)((SRm0 >> lane) & 1ull);
        const int f1 = (int)((SRm1 >> lane) & 1ull);
        const int f2 = (int)((SRm2 >> lane) & 1ull);
        if (f0 && lane != cur)         u0 += minVal - spc_lds[xx0];
        if (f1 && (lane + 64) != cur)  u1 += minVal - spc_lds[xx1];
        if (f2 && (lane + 128) != cur) u2 += minVal - spc_lds[xx2];
        if (sc0) v0 -= (minVal - spc0);
        if (sc1) v1 -= (minVal - spc1);
        if (sc2) v2 -= (minVal - spc2);

        // ---- augment along stored path (R5) ----
        int j = sink;
        while (true) {
            const int pj = GET_I3(p, j);
            SET_I3(yy, j, pj);
            const int nj = GET_I3(xx, pj);
            SET_I3(xx, pj, j);
            if (pj == cur) break;
            j = nj;
        }
    }

    // ---- CE partial: sum_r (lse[r] - pred[r][tgt[col4row[r]]]) ----
    float part = 0.f;
    {
        const int tc0 = tgt_lds[xx0], tc1 = tgt_lds[xx1], tc2 = tgt_lds[xx2];
        part += lse_lds[lane]       - predb[(size_t)lane * CC + tc0];
        part += lse_lds[lane + 64]  - predb[(size_t)(lane + 64) * CC + tc1];
        part += lse_lds[lane + 128] - predb[(size_t)(lane + 128) * CC + tc2];
    }
    part = wave_sum64(part);
    if (lane == 0) ws_part[b] = part;
}

__launch_bounds__(64)
__global__ void reduce_kernel(const float* __restrict__ ws_part,
                              float* __restrict__ out) {
    int lane = threadIdx.x;
    float s = ws_part[lane] + ws_part[lane + 64];
    s = wave_sum64(s);
    if (lane == 0) out[0] = s / (float)(BB * QQ);
}

extern "C" void kernel_launch(void* const* d_in, const int* in_sizes, int n_in,
                              void* d_out, int out_size, void* d_ws, size_t ws_size,
                              hipStream_t stream) {
    const float* pred = (const float*)d_in[0];
    const int* targets = (const int*)d_in[1];
    float* out = (float*)d_out;
    float* ws = (float*)d_ws;

    const int lds_bytes = (QQ * QQ + 3 * QQ) * (int)sizeof(float);  // 149760 B

    hipLaunchKernelGGL(hungarian_kernel, dim3(BB), dim3(256), lds_bytes, stream,
                       pred, targets, ws);
    hipLaunchKernelGGL(reduce_kernel, dim3(1), dim3(64), 0, stream, ws, out);
}

// Round 11
// 837.363 us; speedup vs baseline: 1.1053x; 1.1053x over previous
//
#include <hip/hip_runtime.h>
#include <math.h>

// HungarianLoss: B=128 samples, each a 192x192 LSAP on
// cost[q][j] = -softmax(pred[q])[tgt[j]], then mean CE with matched classes.
//
// FINAL = R5 (best measured: 837us): sequential JV shortest augmenting path
// from zero duals, 4-wave cost fill, all solver state in registers 3/lane,
// packed u32 (key|col) single-pass argmin reduce (4 DPP + 4 readlane + s_min).
// Ledger of failed variants (all regressed, reverted):
//  R3/R4 colmin-dual init & lapjv row-reduction (+settles on degenerate ties)
//  R6 b96 layout + sv-fold + running keys (+22us)
//  R7 capacitated class-dedup (+315us)
//  R8 speculative next-row prefetch w/ minsub reduce (+271us)
//  R9/R10 row4col-in-key next-row decode (+67..+89us)
// Per-settle chain ~210cy: ds_read(~120) -> relax -> fkey pack -> reduce(~60)
// -> rj readlane -> next read. Latency-floor-bound; not BW/compute bound.

#define BB 128
#define QQ 192
#define CC 512
#define NBIG 1e30f

template<int CTRL>
__device__ __forceinline__ int dpp_mov(int x) {
    return __builtin_amdgcn_update_dpp(x, x, CTRL, 0xf, 0xf, false);
}

__device__ __forceinline__ int readlane_i(int v, int l) {
    return __builtin_amdgcn_readlane(v, l);
}
__device__ __forceinline__ float readlane_f(float v, int l) {
    return __int_as_float(__builtin_amdgcn_readlane(__float_as_int(v), l));
}
__device__ __forceinline__ unsigned umin_(unsigned a, unsigned b) { return a < b ? a : b; }

// full 64-lane reduces for the fill phase (validated R1-R10)
__device__ __forceinline__ float wave_max64(float x) {
    x = fmaxf(x, __int_as_float(dpp_mov<0x111>(__float_as_int(x))));
    x = fmaxf(x, __int_as_float(dpp_mov<0x112>(__float_as_int(x))));
    x = fmaxf(x, __int_as_float(dpp_mov<0x114>(__float_as_int(x))));
    x = fmaxf(x, __int_as_float(dpp_mov<0x118>(__float_as_int(x))));
    x = fmaxf(x, __int_as_float(dpp_mov<0x142>(__float_as_int(x))));
    x = fmaxf(x, __int_as_float(dpp_mov<0x143>(__float_as_int(x))));
    return __int_as_float(__builtin_amdgcn_readlane(__float_as_int(x), 63));
}
__device__ __forceinline__ float wave_sum64(float x) {
    x += __int_as_float(dpp_mov<0x111>(__float_as_int(x)));
    x += __int_as_float(dpp_mov<0x112>(__float_as_int(x)));
    x += __int_as_float(dpp_mov<0x114>(__float_as_int(x)));
    x += __int_as_float(dpp_mov<0x118>(__float_as_int(x)));
    x += __int_as_float(dpp_mov<0x142>(__float_as_int(x)));
    x += __int_as_float(dpp_mov<0x143>(__float_as_int(x)));
    return __int_as_float(__builtin_amdgcn_readlane(__float_as_int(x), 63));
}

// packed-key min over 64 lanes: 4 DPP row_shr levels (16-lane rows) then
// 4 readlanes + scalar mins (cheaper than 2 row_bcast DPP levels).
__device__ __forceinline__ unsigned wave_min_pk(unsigned x) {
    x = umin_(x, (unsigned)dpp_mov<0x111>((int)x));
    x = umin_(x, (unsigned)dpp_mov<0x112>((int)x));
    x = umin_(x, (unsigned)dpp_mov<0x114>((int)x));
    x = umin_(x, (unsigned)dpp_mov<0x118>((int)x));
    unsigned a = (unsigned)readlane_i((int)x, 15);
    unsigned b = (unsigned)readlane_i((int)x, 31);
    unsigned c = (unsigned)readlane_i((int)x, 47);
    unsigned d = (unsigned)readlane_i((int)x, 63);
    return umin_(umin_(a, b), umin_(c, d));
}

// sign-aware monotonic float->u32 key (handles tiny negative reduced costs)
__device__ __forceinline__ unsigned fkey(float f) {
    unsigned b = __float_as_uint(f);
    return b ^ (((unsigned)((int)b >> 31)) | 0x80000000u);
}

// distributed-register accessors (idx -> owner lane idx&63, slot idx>>6)
#define GET_I3(a, idx) readlane_i((((idx)>>6)==0) ? a##0 : ((((idx)>>6)==1) ? a##1 : a##2), (idx)&63)
#define GET_F3(a, idx) readlane_f((((idx)>>6)==0) ? a##0 : ((((idx)>>6)==1) ? a##1 : a##2), (idx)&63)
#define SET_I3(a, idx, val) do { const int _s=(idx)>>6, _l=(idx)&63; \
    if (_s==0) { if (lane==_l) a##0=(val); } \
    else if (_s==1) { if (lane==_l) a##1=(val); } \
    else { if (lane==_l) a##2=(val); } } while(0)

__launch_bounds__(256)
__global__ void hungarian_kernel(const float* __restrict__ pred,
                                 const int* __restrict__ targets,
                                 float* __restrict__ ws_part) {
    const int b = blockIdx.x;
    const int lane = threadIdx.x & 63;
    const int wv = threadIdx.x >> 6;

    extern __shared__ float smem[];
    float* cost    = smem;                   // [QQ*QQ] read-only after fill
    float* spc_lds = cost + QQ * QQ;         // [QQ] per-solve spc dump
    float* lse_lds = spc_lds + QQ;           // [QQ]
    int*   tgt_lds = (int*)(lse_lds + QQ);   // [QQ]

    // ---- targets ----
    const int t0 = targets[b * QQ + lane];
    const int t1 = targets[b * QQ + lane + 64];
    const int t2 = targets[b * QQ + lane + 128];
    if (wv == 0) { tgt_lds[lane] = t0; tgt_lds[lane + 64] = t1; tgt_lds[lane + 128] = t2; }

    // ---- fill: 4 waves, 48 rows each (validated R4) ----
    const float* predb = pred + (size_t)b * QQ * CC;
    {
        const int q0 = wv * 48, q1 = q0 + 48;
        float x[8];
        #pragma unroll
        for (int k = 0; k < 8; k++) x[k] = predb[(size_t)q0 * CC + lane + 64 * k];
        for (int q = q0; q < q1; q++) {
            const float* row = predb + (size_t)q * CC;
            float g0 = row[t0], g1 = row[t1], g2 = row[t2];
            float xn[8];
            if (q + 1 < q1) {
                const float* nrow = row + CC;
                #pragma unroll
                for (int k = 0; k < 8; k++) xn[k] = nrow[lane + 64 * k];
            }
            float mx = x[0];
            #pragma unroll
            for (int k = 1; k < 8; k++) mx = fmaxf(mx, x[k]);
            mx = wave_max64(mx);
            float s = 0.f;
            #pragma unroll
            for (int k = 0; k < 8; k++) s += expf(x[k] - mx);
            s = wave_sum64(s);
            float lse = mx + logf(s);
            if (lane == 0) lse_lds[q] = lse;
            cost[q * QQ + lane]       = -expf(g0 - lse);
            cost[q * QQ + lane + 64]  = -expf(g1 - lse);
            cost[q * QQ + lane + 128] = -expf(g2 - lse);
            #pragma unroll
            for (int k = 0; k < 8; k++) x[k] = xn[k];
        }
    }
    __syncthreads();
    if (wv != 0) return;
    // single wave from here: in-wave LDS ordering via waitcnt, no barriers.

    // ---- solver state: 3 rows + 3 cols per lane ----
    float u0 = 0.f, u1 = 0.f, u2 = 0.f;   // row duals
    float v0 = 0.f, v1 = 0.f, v2 = 0.f;   // col duals
    int   c0 = -1, c1 = -1, c2 = -1;      // col4row
    int   r0 = -1, r1 = -1, r2 = -1;      // row4col

    // ---- sequential JV shortest augmenting path (R2 semantics) ----
    for (int cur = 0; cur < QQ; cur++) {
        float spc0 = NBIG, spc1 = NBIG, spc2 = NBIG;
        int   p0 = 0, p1 = 0, p2 = 0;
        int   sc0 = 0, sc1 = 0, sc2 = 0;
        unsigned long long SRm0 = 0, SRm1 = 0, SRm2 = 0;  // scanned-row masks (scalar)
        int   i = cur;
        float minVal = 0.f;
        int   sink;

        while (true) {
            {   // SR[i] = 1 (scalar mask ops, off VALU critical path)
                const int is = i >> 6, il = i & 63;
                if (is == 0)      SRm0 |= 1ull << il;
                else if (is == 1) SRm1 |= 1ull << il;
                else              SRm2 |= 1ull << il;
            }
            const float* crow = cost + i * QQ;
            const float cA = crow[lane];
            const float cB = crow[lane + 64];
            const float cD = crow[lane + 128];
            const float ui = GET_F3(u, i);   // overlaps the ds_read latency

            // relax (reference ordering + settled guard semantics)
            float rA = ((minVal + cA) - ui) - v0;  rA = sc0 ? NBIG : rA;
            if (rA < spc0) { spc0 = rA; p0 = i; }
            float rB = ((minVal + cB) - ui) - v1;  rB = sc1 ? NBIG : rB;
            if (rB < spc1) { spc1 = rB; p1 = i; }
            float rD = ((minVal + cD) - ui) - v2;  rD = sc2 ? NBIG : rD;
            if (rD < spc2) { spc2 = rD; p2 = i; }

            // packed (key|col) argmin: one u32 reduce gives min AND argmin;
            // exact ties (duplicate columns) break to lowest col like jnp.argmin
            unsigned pkA = sc0 ? 0xFFFFFFFFu : ((fkey(spc0) & 0xFFFFFF00u) | (unsigned)lane);
            unsigned pkB = sc1 ? 0xFFFFFFFFu : ((fkey(spc1) & 0xFFFFFF00u) | (unsigned)(lane + 64));
            unsigned pkD = sc2 ? 0xFFFFFFFFu : ((fkey(spc2) & 0xFFFFFF00u) | (unsigned)(lane + 128));
            const unsigned pk = wave_min_pk(umin_(umin_(pkA, pkB), pkD));
            const int jstar = (int)(pk & 255u);
            const int os = jstar >> 6, ol = jstar & 63;

            // exact minVal from the winner's spc (parallel to next-row chain)
            minVal = readlane_f(os == 0 ? spc0 : (os == 1 ? spc1 : spc2), ol);
            sc0 |= (jstar == lane);
            sc1 |= (jstar == lane + 64);
            sc2 |= (jstar == lane + 128);
            const int rj = readlane_i(os == 0 ? r0 : (os == 1 ? r1 : r2), ol);
            if (rj < 0) { sink = jstar; break; }
            i = rj;
        }

        // ---- dual updates ----
        u0 += (cur == lane) ? minVal : 0.f;
        u1 += (cur == lane + 64) ? minVal : 0.f;
        u2 += (cur == lane + 128) ? minVal : 0.f;
        spc_lds[lane] = spc0; spc_lds[lane + 64] = spc1; spc_lds[lane + 128] = spc2;
        const int f0 = (int)((SRm0 >> lane) & 1ull);
        const int f1 = (int)((SRm1 >> lane) & 1ull);
        const int f2 = (int)((SRm2 >> lane) & 1ull);
        if (f0 && lane != cur)         u0 += minVal - spc_lds[c0];
        if (f1 && (lane + 64) != cur)  u1 += minVal - spc_lds[c1];
        if (f2 && (lane + 128) != cur) u2 += minVal - spc_lds[c2];
        if (sc0) v0 -= (minVal - spc0);
        if (sc1) v1 -= (minVal - spc1);
        if (sc2) v2 -= (minVal - spc2);

        // ---- augment along stored path ----
        int j = sink;
        while (true) {
            const int pj = GET_I3(p, j);
            SET_I3(r, j, pj);
            const int nj = GET_I3(c, pj);
            SET_I3(c, pj, j);
            if (pj == cur) break;
            j = nj;
        }
    }

    // ---- CE partial: sum_r (lse[r] - pred[r][tgt[col4row[r]]]) ----
    float part = 0.f;
    {
        const int tc0 = tgt_lds[c0], tc1 = tgt_lds[c1], tc2 = tgt_lds[c2];
        part += lse_lds[lane]       - predb[(size_t)lane * CC + tc0];
        part += lse_lds[lane + 64]  - predb[(size_t)(lane + 64) * CC + tc1];
        part += lse_lds[lane + 128] - predb[(size_t)(lane + 128) * CC + tc2];
    }
    part = wave_sum64(part);
    if (lane == 0) ws_part[b] = part;
}

__launch_bounds__(64)
__global__ void reduce_kernel(const float* __restrict__ ws_part,
                              float* __restrict__ out) {
    int lane = threadIdx.x;
    float s = ws_part[lane] + ws_part[lane + 64];
    s = wave_sum64(s);
    if (lane == 0) out[0] = s / (float)(BB * QQ);
}

extern "C" void kernel_launch(void* const* d_in, const int* in_sizes, int n_in,
                              void* d_out, int out_size, void* d_ws, size_t ws_size,
                              hipStream_t stream) {
    const float* pred = (const float*)d_in[0];
    const int* targets = (const int*)d_in[1];
    float* out = (float*)d_out;
    float* ws = (float*)d_ws;

    const int lds_bytes = (QQ * QQ + 3 * QQ) * (int)sizeof(float);  // 149760 B

    hipLaunchKernelGGL(hungarian_kernel, dim3(BB), dim3(256), lds_bytes, stream,
                       pred, targets, ws);
    hipLaunchKernelGGL(reduce_kernel, dim3(1), dim3(64), 0, stream, ws, out);
}